// Round 11
// baseline (238.922 us; speedup 1.0000x reference)
//
#include <hip/hip_runtime.h>
#include <hip/hip_fp16.h>
#include <stdint.h>

#define B_    64
#define T_    512
#define OBS_  128
#define FEAT_ 512
#define H_    256
#define G_    768
#define BT_   32768
#define NSLOT 16

typedef _Float16 f16x8 __attribute__((ext_vector_type(8)));
typedef float    f32x4 __attribute__((ext_vector_type(4)));

__device__ __forceinline__ uint32_t h2u(__half2 h){ union{ __half2 h; uint32_t u; } c; c.h = h; return c.u; }
__device__ __forceinline__ __half2 u2h(uint32_t u){ union{ uint32_t u; __half2 h; } c; c.u = u; return c.h; }

// swizzled LDS byte offset: [rows][8 chunks of 16B], chunk ^= row&7
__device__ __forceinline__ int sw(int r, int c) { return r * 128 + ((c ^ (r & 7)) << 4); }

__device__ __forceinline__ uint4 cvt8(float4 a, float4 b) {
    uint4 u;
    u.x = h2u(__floats2half2_rn(a.x, a.y));
    u.y = h2u(__floats2half2_rn(a.z, a.w));
    u.z = h2u(__floats2half2_rn(b.x, b.y));
    u.w = h2u(__floats2half2_rn(b.z, b.w));
    return u;
}

// ---------------------------------------------------------------------------
// Fused feat+gx GEMM v2. Identical math/layout to r10 (passed); ONE change:
// r3-proven load hoisting -- next W-tile's global loads issue AFTER the
// second barrier and BEFORE compute, so their latency hides under compute +
// barriers instead of sitting exposed between the two barriers (r10 counters:
// MfmaUtil 13%, VALUBusy 12%, HBM 9% -- pure latency-bound at 1 block/CU).
// ---------------------------------------------------------------------------
__global__ __launch_bounds__(512, 2)
void fused_gemm(const float* __restrict__ obs, const __half* __restrict__ W1h,
                const __half* __restrict__ Wihh, const float* __restrict__ b1,
                const float* __restrict__ bih, uint32_t* __restrict__ gxC)
{
    __shared__ __align__(16) __half smem[49152];   // 96KB: obsA 32 | featL 32 | Bs 32
    __half* obsA  = smem;            // [2 panels of 16KB][128r][64h] swizzled
    __half* featL = smem + 16384;    // same layout
    __half* BsS   = smem + 32768;    // stage1: 128x64; stage2: 256x64

    const int bid = blockIdx.x;
    const int m0 = (bid & 255) * 128;
    const int n0 = (bid >> 8) * 256;
    const int tid = threadIdx.x;
    const int lane = tid & 63, w = tid >> 6;
    const int wm = w >> 2, wn = w & 3;     // 2x4 waves
    const int l15 = lane & 15, lq = lane >> 4;

    // ---- stage obs tile once (fp32 -> fp16, both K-panels) ----
    {
        const int r = tid >> 2, c0 = (tid & 3) * 4;
        const float* ap = obs + (size_t)(m0 + r) * OBS_ + c0 * 8;
        #pragma unroll
        for (int c = 0; c < 4; ++c) {
            const float4 f0 = ((const float4*)ap)[c * 2];
            const float4 f1 = ((const float4*)ap)[c * 2 + 1];
            const int cc = c0 + c;
            *(uint4*)((char*)obsA + (cc >> 3) * 16384 + sw(r, cc & 7)) = cvt8(f0, f1);
        }
    }

    // ---- B-tile staging plumbing (regs -> LDS; loads hoisted) ----
    uint4 sb[4];
    const int sr = tid >> 1, scb = (tid & 1) * 4;   // staging row / chunk base
    auto load_s1 = [&](int j, int kt) {             // W1 tile 128x64
        if (tid < 256) {
            const __half* bp = W1h + (size_t)(j * 128 + sr) * OBS_ + kt * 64 + scb * 8;
            #pragma unroll
            for (int c = 0; c < 4; ++c) sb[c] = ((const uint4*)bp)[c];
        }
    };
    auto load_s2 = [&](int j, int kt2) {            // Wih tile 256x64
        const __half* bp = Wihh + (size_t)(n0 + sr) * FEAT_ + j * 128 + kt2 * 64 + scb * 8;
        #pragma unroll
        for (int c = 0; c < 4; ++c) sb[c] = ((const uint4*)bp)[c];
    };
    auto write_s1 = [&]() {
        if (tid < 256) {
            #pragma unroll
            for (int c = 0; c < 4; ++c) *(uint4*)((char*)BsS + sw(sr, scb + c)) = sb[c];
        }
    };
    auto write_s2 = [&]() {
        #pragma unroll
        for (int c = 0; c < 4; ++c) *(uint4*)((char*)BsS + sw(sr, scb + c)) = sb[c];
    };

    f32x4 acc2[4][4];
    #pragma unroll
    for (int i = 0; i < 4; ++i)
        #pragma unroll
        for (int jj = 0; jj < 4; ++jj) { const f32x4 z = {0.f,0.f,0.f,0.f}; acc2[i][jj] = z; }

    load_s1(0, 0);                                  // prologue prefetch

    for (int j = 0; j < 4; ++j) {
        // ---- stage 1: feat_sub[128x128] = relu(obs @ W1^T + b1), K=128 ----
        f32x4 acc1[4][2];
        #pragma unroll
        for (int i = 0; i < 4; ++i)
            #pragma unroll
            for (int jj = 0; jj < 2; ++jj) { const f32x4 z = {0.f,0.f,0.f,0.f}; acc1[i][jj] = z; }
        #pragma unroll
        for (int kt = 0; kt < 2; ++kt) {
            __syncthreads();                        // Bs free (prev compute done)
            write_s1();
            __syncthreads();
            if (kt == 0) load_s1(j, 1);             // hoisted: in flight across compute
            else         load_s2(j, 0);
            #pragma unroll
            for (int kc = 0; kc < 2; ++kc) {
                f16x8 af[4], bf[2];
                #pragma unroll
                for (int mi = 0; mi < 4; ++mi)
                    af[mi] = *(const f16x8*)((const char*)obsA + kt * 16384 +
                                             sw(wm * 64 + mi * 16 + l15, kc * 4 + lq));
                #pragma unroll
                for (int ni = 0; ni < 2; ++ni)
                    bf[ni] = *(const f16x8*)((const char*)BsS +
                                             sw(wn * 32 + ni * 16 + l15, kc * 4 + lq));
                #pragma unroll
                for (int mi = 0; mi < 4; ++mi)
                    #pragma unroll
                    for (int ni = 0; ni < 2; ++ni)
                        acc1[mi][ni] = __builtin_amdgcn_mfma_f32_16x16x32_f16(af[mi], bf[ni], acc1[mi][ni], 0, 0, 0);
            }
        }
        // ---- feat_sub -> featL (bias+relu, fp16, panel-swizzled) ----
        #pragma unroll
        for (int ni = 0; ni < 2; ++ni) {
            const int col = wn * 32 + ni * 16 + l15;
            const float bv = b1[j * 128 + col];
            #pragma unroll
            for (int mi = 0; mi < 4; ++mi) {
                const f32x4 d = acc1[mi][ni];
                #pragma unroll
                for (int rr = 0; rr < 4; ++rr) {
                    const float v = fmaxf(d[rr] + bv, 0.0f);
                    const uint32_t u = (uint32_t)__half_as_ushort(__float2half(v));
                    const uint32_t nb = (uint32_t)__shfl_xor((int)u, 1);
                    if (!(lane & 1)) {
                        const int row = wm * 64 + mi * 16 + lq * 4 + rr;
                        *(uint32_t*)((char*)featL + (col >> 6) * 16384 + row * 128 +
                                     ((((col >> 3) & 7) ^ (row & 7)) << 4) + (col & 7) * 2) = u | (nb << 16);
                    }
                }
            }
        }
        // ---- stage 2: gx_acc += feat_sub @ Wih^T (two BK=64 chunks) ----
        #pragma unroll
        for (int kt2 = 0; kt2 < 2; ++kt2) {
            __syncthreads();                        // featL visible; Bs free
            write_s2();
            __syncthreads();
            if (kt2 == 0)      load_s2(j, 1);       // hoisted
            else if (j < 3)    load_s1(j + 1, 0);
            #pragma unroll
            for (int kc = 0; kc < 2; ++kc) {
                f16x8 af[4], bf[4];
                #pragma unroll
                for (int mi = 0; mi < 4; ++mi)
                    af[mi] = *(const f16x8*)((const char*)featL + kt2 * 16384 +
                                             sw(wm * 64 + mi * 16 + l15, kc * 4 + lq));
                #pragma unroll
                for (int ni = 0; ni < 4; ++ni)
                    bf[ni] = *(const f16x8*)((const char*)BsS +
                                             sw(wn * 64 + ni * 16 + l15, kc * 4 + lq));
                #pragma unroll
                for (int mi = 0; mi < 4; ++mi)
                    #pragma unroll
                    for (int ni = 0; ni < 4; ++ni)
                        acc2[mi][ni] = __builtin_amdgcn_mfma_f32_16x16x32_f16(af[mi], bf[ni], acc2[mi][ni], 0, 0, 0);
            }
        }
    }

    // ---- epilogue: Cs staging (reuses obsA+featL), 512B-contiguous rows ----
    __syncthreads();
    uint32_t* Cs = (uint32_t*)smem;                // [128][128] uint32 = 64KB
    #pragma unroll
    for (int ni = 0; ni < 4; ++ni) {
        const int col = wn * 64 + ni * 16 + l15;
        const float bv = bih[n0 + col];
        #pragma unroll
        for (int mi = 0; mi < 4; ++mi) {
            const f32x4 d = acc2[mi][ni];
            #pragma unroll
            for (int rr = 0; rr < 4; ++rr) {
                const float v = d[rr] + bv;
                const uint32_t u = (uint32_t)__half_as_ushort(__float2half(v));
                const uint32_t nb = (uint32_t)__shfl_xor((int)u, 1);
                if (!(lane & 1))
                    Cs[(wm * 64 + mi * 16 + lq * 4 + rr) * 128 + (col >> 1)] = u | (nb << 16);
            }
        }
    }
    __syncthreads();
    const int orow = tid >> 2, oq = (tid & 3) * 32;    // 4 thr x 128B per row
    #pragma unroll
    for (int c = 0; c < 8; ++c) {
        const uint4 val = *(const uint4*)&Cs[orow * 128 + oq + c * 4];
        *(uint4*)(gxC + (size_t)(m0 + orow) * (G_ / 2) + (n0 >> 1) + oq + c * 4) = val;
    }
}

// ---------------------------------------------------------------------------
// Weight packs (unchanged -- passed r8/r9/r10). pack_whh zeroes qctl and
// splits W_hh into WhhR (reg K-chunks 0..5) + WhhL (LDS K-chunks 6..7).
// ---------------------------------------------------------------------------
__global__ void pack_half(const float* __restrict__ in, uint32_t* __restrict__ out, int n2)
{
    int i = blockIdx.x * 256 + threadIdx.x;
    if (i < n2) {
        float2 f = ((const float2*)in)[i];
        out[i] = h2u(__floats2half2_rn(f.x, f.y));
    }
}

__global__ void pack_whh(const float* __restrict__ Whh, uint32_t* __restrict__ outR,
                         uint32_t* __restrict__ outL, int* __restrict__ qctl)
{
    if (blockIdx.x == 0 && threadIdx.x == 0) { qctl[0] = 0; qctl[1] = 0; }
    int p = blockIdx.x * 256 + threadIdx.x;
    if (p >= 512 * 192) return;
    const int v4 = p >> 2, sub = p & 3;
    const int t = v4 / 48, ic = v4 - t * 48;
    const int i = ic >> 3, c = ic & 7;
    const int w = t >> 6, lane = t & 63;
    const int row = w * 96 + i * 16 + (lane & 15);
    const int kb = c * 32 + ((lane >> 4) << 3) + sub * 2;
    const uint32_t val = h2u(__floats2half2_rn(Whh[row * 256 + kb], Whh[row * 256 + kb + 1]));
    if (c < 6) outR[(t * 36 + i * 6 + c) * 4 + sub] = val;
    else       outL[(((i << 1) + (c - 6)) * 512 + t) * 4 + sub] = val;
}

// ---------------------------------------------------------------------------
// Segment builder (unchanged -- passed r6/r8/r9/r10).
// ---------------------------------------------------------------------------
__global__ __launch_bounds__(512)
void seg_build(const int* __restrict__ masks, int* __restrict__ queue,
               int* __restrict__ qtail)
{
    __shared__ int sc[512];
    __shared__ int starts[512];
    __shared__ int cshr[2];
    const int b = blockIdx.x, s = threadIdx.x;
    const int is = (s == 0) || (masks[b * (T_ - 1) + s - 1] == 0);
    sc[s] = is;
    __syncthreads();
    #pragma unroll
    for (int off = 1; off < 512; off <<= 1) {
        int v = (s >= off) ? sc[s - off] : 0;
        __syncthreads();
        sc[s] += v;
        __syncthreads();
    }
    if (is) starts[sc[s] - 1] = s;
    if (s == 511) cshr[0] = sc[511];
    __syncthreads();
    const int cnt = cshr[0];
    int valid = 0, st = 0, ln = 0;
    if (s < cnt) {
        st = starts[s];
        const int nxt = (s + 1 < cnt) ? starts[s + 1] : T_;
        ln = nxt - st;
        valid = (st == 0 || ln >= 2) ? 1 : 0;
    }
    sc[s] = valid;
    __syncthreads();
    #pragma unroll
    for (int off = 1; off < 512; off <<= 1) {
        int v = (s >= off) ? sc[s - off] : 0;
        __syncthreads();
        sc[s] += v;
        __syncthreads();
    }
    if (s == 511) cshr[1] = atomicAdd(qtail, sc[511]);
    __syncthreads();
    if (valid) queue[cshr[1] + sc[s] - 1] = (b << 19) | (st << 10) | ln;
}

// ---------------------------------------------------------------------------
// Pre-pass, grid-stride (unchanged -- passed r8/r9/r10).
// ---------------------------------------------------------------------------
__global__ __launch_bounds__(256)
void h0pre(const __half* __restrict__ gx, const float* __restrict__ bhh,
           const int* __restrict__ masks, uint32_t* __restrict__ hs2)
{
    for (int row = blockIdx.x; row < B_ * (T_ - 1); row += gridDim.x) {
        if (masks[row] != 0) continue;
        const int b = row / (T_ - 1), t = 1 + row - b * (T_ - 1);
        const int e = threadIdx.x;
        const __half* grow = gx + (size_t)(b * T_ + t) * 768;
        const float gxr = __half2float(grow[e]);
        const float gxz = __half2float(grow[e + 256]);
        const float gxn = __half2float(grow[e + 512]);
        const float rg = 1.f / (1.f + exp2f(-(gxr + bhh[e]) * 1.44269504f));
        const float zg = 1.f / (1.f + exp2f(-(gxz + bhh[e + 256]) * 1.44269504f));
        const float nin = gxn + rg * bhh[e + 512];
        const float e2x = exp2f(nin * 2.885390082f);
        const float ng = 1.f - 2.f / (e2x + 1.f);
        const float hnew = (1.f - zg) * ng;     // h_prev = 0
        const float other = __shfl_xor(hnew, 1);
        if (!(e & 1)) hs2[(size_t)(b * T_ + t) * 128 + (e >> 1)] = h2u(__floats2half2_rn(hnew, other));
    }
}

// ---------------------------------------------------------------------------
// MFMA slot-parallel GRU v3 (unchanged -- passed r8/r9/r10).
// ---------------------------------------------------------------------------
__global__ __launch_bounds__(512, 2)
void gru_mfma(const __half* __restrict__ gx, const uint4* __restrict__ WhhR,
              const uint4* __restrict__ WhhL, const float* __restrict__ bhh,
              const float* __restrict__ h0, const int* __restrict__ queue,
              const int* __restrict__ qctl, uint32_t* __restrict__ hs2)
{
    __shared__ __align__(16) __half Hl[NSLOT * 256];   // 8KB, granule-swizzled
    __shared__ __align__(16) __half Plh[NSLOT * 784];  // 24.5KB gh (fp16)
    __shared__ __align__(16) uint4  Wl[12 * 512];      // 98KB W_hh K-chunks 6..7
    __shared__ float Bl[G_];
    __shared__ int s_end[NSLOT], s_row[NSLOT], s_act[NSLOT], s_nxt[NSLOT];
    __shared__ int cur;

    const int tid = threadIdx.x;
    const int lane = tid & 63, w = tid >> 6;
    const int s = tid >> 5, g32 = tid & 31, e0 = g32 * 8;
    const int col = lane & 15, lq = lane >> 4;

    f16x8 wr[36];
    {
        const f16x8* wp = (const f16x8*)(WhhR + (size_t)tid * 36);
        #pragma unroll
        for (int i = 0; i < 36; ++i) wr[i] = wp[i];
    }
    #pragma unroll
    for (int i = 0; i < 12; ++i) Wl[i * 512 + tid] = WhhL[i * 512 + tid];
    if (tid < 384) { Bl[tid] = bhh[tid]; Bl[tid + 384] = bhh[tid + 384]; }
    { const uint4 z4 = {0u, 0u, 0u, 0u}; *(uint4*)((char*)Hl + tid * 16) = z4; }

    const int NQ = qctl[0];
    const int gb = blockIdx.x;
    const int lo = (int)(((long long)NQ * gb) >> 8);
    const int hi = (int)(((long long)NQ * (gb + 1)) >> 8);
    if (tid == 0) cur = lo + NSLOT;
    __syncthreads();

    {
        int e = -1;
        if (lo + s < hi) e = queue[lo + s];
        if (e >= 0) {
            const int ln = e & 1023, st = (e >> 10) & 511, nb = e >> 19;
            uint4 hseed;
            if (st == 0) {
                const float4 a = *(const float4*)(h0 + nb * 256 + e0);
                const float4 b = *(const float4*)(h0 + nb * 256 + e0 + 4);
                hseed = cvt8(a, b);
                if (g32 == 0) { s_row[s] = nb * T_; s_end[s] = nb * T_ + ln; }
            } else {
                hseed = *(const uint4*)(hs2 + (size_t)(nb * T_ + st) * 128 + g32 * 4);
                if (g32 == 0) { s_row[s] = nb * T_ + st + 1; s_end[s] = nb * T_ + st + ln; }
            }
            *(uint4*)((char*)Hl + s * 512 + ((g32 ^ (s & 7)) << 4)) = hseed;
            if (g32 == 0) {
                s_act[s] = 1;
                const int p = atomicAdd(&cur, 1);
                s_nxt[s] = (p < hi) ? queue[p] : -1;
            }
        } else if (g32 == 0) {
            s_act[s] = 0; s_nxt[s] = -1; s_row[s] = 0; s_end[s] = 0;
        }
    }
    __syncthreads();

    for (;;) {
        bool alive = false;
        #pragma unroll
        for (int i = 0; i < NSLOT; ++i) alive |= (s_act[i] != 0);
        if (!alive) break;

        // ---- phase X ----
        const int myrow = s_row[s];
        const int nxte = s_nxt[s];
        const __half* grow = gx + (size_t)myrow * G_;
        const f16x8 gr = *(const f16x8*)(grow + e0);
        const f16x8 gz = *(const f16x8*)(grow + 256 + e0);
        const f16x8 gn = *(const f16x8*)(grow + 512 + e0);
        uint4 su = {0u, 0u, 0u, 0u};
        if (nxte >= 0) {
            const int st = (nxte >> 10) & 511, nb = nxte >> 19;
            if (st == 0) {
                const float4 a = *(const float4*)(h0 + nb * 256 + e0);
                const float4 b = *(const float4*)(h0 + nb * 256 + e0 + 4);
                su = cvt8(a, b);
            } else {
                su = *(const uint4*)(hs2 + (size_t)(nb * T_ + st) * 128 + g32 * 4);
            }
        }
        f16x8 bfv[8];
        #pragma unroll
        for (int c = 0; c < 8; ++c)
            bfv[c] = *(const f16x8*)((const char*)Hl + col * 512 +
                                     ((((c << 2) + lq) ^ (col & 7)) << 4));
        f32x4 acc[6];
        #pragma unroll
        for (int i = 0; i < 6; ++i) { const f32x4 z = {0.f, 0.f, 0.f, 0.f}; acc[i] = z; }
        #pragma unroll
        for (int c = 0; c < 6; ++c)
            #pragma unroll
            for (int i = 0; i < 6; ++i)
                acc[i] = __builtin_amdgcn_mfma_f32_16x16x32_f16(wr[i * 6 + c], bfv[c], acc[i], 0, 0, 0);
        #pragma unroll
        for (int c2 = 0; c2 < 2; ++c2)
            #pragma unroll
            for (int i = 0; i < 6; ++i) {
                const f16x8 wlt = *(const f16x8*)&Wl[(i * 2 + c2) * 512 + tid];
                acc[i] = __builtin_amdgcn_mfma_f32_16x16x32_f16(wlt, bfv[6 + c2], acc[i], 0, 0, 0);
            }
        #pragma unroll
        for (int i = 0; i < 6; ++i) {
            uint2 ph;
            ph.x = h2u(__floats2half2_rn(acc[i][0], acc[i][1]));
            ph.y = h2u(__floats2half2_rn(acc[i][2], acc[i][3]));
            *(uint2*)(Plh + col * 784 + (w * 96 + i * 16 + lq * 4)) = ph;
        }
        asm volatile("s_waitcnt lgkmcnt(0)" ::: "memory");
        __builtin_amdgcn_s_barrier();

        // ---- phase Y ----
        if (s_act[s]) {
            const __half* Pr = Plh + s * 784;
            const f16x8 R  = *(const f16x8*)(Pr + e0);
            const f16x8 Z  = *(const f16x8*)(Pr + 256 + e0);
            const f16x8 Nn = *(const f16x8*)(Pr + 512 + e0);
            const f32x4 br0 = *(const f32x4*)(Bl + e0),       br1 = *(const f32x4*)(Bl + e0 + 4);
            const f32x4 bz0 = *(const f32x4*)(Bl + 256 + e0), bz1 = *(const f32x4*)(Bl + 256 + e0 + 4);
            const f32x4 bn0 = *(const f32x4*)(Bl + 512 + e0), bn1 = *(const f32x4*)(Bl + 512 + e0 + 4);
            const uint4 hp4 = *(const uint4*)((const char*)Hl + s * 512 + ((g32 ^ (s & 7)) << 4));
            const __half2 q0 = u2h(hp4.x), q1 = u2h(hp4.y), q2 = u2h(hp4.z), q3 = u2h(hp4.w);
            const float hpv[8] = { __low2float(q0), __high2float(q0), __low2float(q1), __high2float(q1),
                                   __low2float(q2), __high2float(q2), __low2float(q3), __high2float(q3) };
            float hn[8];
            #pragma unroll
            for (int j = 0; j < 8; ++j) {
                const float ghr = (float)R[j]  + (j < 4 ? br0[j] : br1[j - 4]);
                const float ghz = (float)Z[j]  + (j < 4 ? bz0[j] : bz1[j - 4]);
                const float ghn = (float)Nn[j] + (j < 4 ? bn0[j] : bn1[j - 4]);
                const float rg = 1.f / (1.f + exp2f(-((float)gr[j] + ghr) * 1.44269504f));
                const float zg = 1.f / (1.f + exp2f(-((float)gz[j] + ghz) * 1.44269504f));
                const float nin = (float)gn[j] + rg * ghn;
                const float ex = exp2f(nin * 2.885390082f);
                const float ng = 1.f - 2.f / (ex + 1.f);
                hn[j] = (1.f - zg) * ng + zg * hpv[j];
            }
            uint4 hp;
            hp.x = h2u(__floats2half2_rn(hn[0], hn[1]));
            hp.y = h2u(__floats2half2_rn(hn[2], hn[3]));
            hp.z = h2u(__floats2half2_rn(hn[4], hn[5]));
            hp.w = h2u(__floats2half2_rn(hn[6], hn[7]));
            *(uint4*)(hs2 + (size_t)myrow * 128 + g32 * 4) = hp;
            if (myrow + 1 < s_end[s]) {
                *(uint4*)((char*)Hl + s * 512 + ((g32 ^ (s & 7)) << 4)) = hp;
                if (g32 == 0) s_row[s] = myrow + 1;
            } else if (nxte >= 0) {
                const int ln = nxte & 1023, st = (nxte >> 10) & 511, nb = nxte >> 19;
                *(uint4*)((char*)Hl + s * 512 + ((g32 ^ (s & 7)) << 4)) = su;
                if (g32 == 0) {
                    if (st == 0) { s_row[s] = nb * T_;          s_end[s] = nb * T_ + ln; }
                    else         { s_row[s] = nb * T_ + st + 1; s_end[s] = nb * T_ + st + ln; }
                    const int p = atomicAdd(&cur, 1);
                    s_nxt[s] = (p < hi) ? queue[p] : -1;
                }
            } else if (g32 == 0) {
                s_act[s] = 0;
            }
        }
        asm volatile("s_waitcnt lgkmcnt(0)" ::: "memory");
        __builtin_amdgcn_s_barrier();
    }
}

// ---------------------------------------------------------------------------
// Heads (unchanged, passed): one wave per output row, hs fp16.
// ---------------------------------------------------------------------------
__global__ __launch_bounds__(256)
void heads_kernel(const uint32_t* __restrict__ hs2, const float* __restrict__ Wa,
                  const float* __restrict__ ba, const float* __restrict__ Wc,
                  const float* __restrict__ bc, const int* __restrict__ action,
                  float* __restrict__ out)
{
    const int wid = threadIdx.x >> 6, lane = threadIdx.x & 63;
    const int row = blockIdx.x * 4 + wid;
    const uint2 hv2 = ((const uint2*)(hs2 + (size_t)row * 128))[lane];
    const __half2 ha = u2h(hv2.x), hb = u2h(hv2.y);
    const float h0f = __low2float(ha), h1f = __high2float(ha);
    const float h2f = __low2float(hb), h3f = __high2float(hb);
    float sums[11];
    #pragma unroll
    for (int n = 0; n < 11; ++n) {
        const float* wrow = (n < 10) ? (Wa + n * 256) : Wc;
        const float4 wv = ((const float4*)wrow)[lane];
        sums[n] = h0f * wv.x + h1f * wv.y + h2f * wv.z + h3f * wv.w;
    }
    #pragma unroll
    for (int n = 0; n < 11; ++n) {
        float v = sums[n];
        #pragma unroll
        for (int off = 32; off; off >>= 1) v += __shfl_xor(v, off);
        sums[n] = v;
    }
    float logits[10];
    #pragma unroll
    for (int n = 0; n < 10; ++n) logits[n] = sums[n] + ba[n];
    const float value = sums[10] + bc[0];
    float mx = logits[0];
    #pragma unroll
    for (int n = 1; n < 10; ++n) mx = fmaxf(mx, logits[n]);
    float ssum = 0.f, sdot = 0.f;
    #pragma unroll
    for (int n = 0; n < 10; ++n) {
        float d = logits[n] - mx;
        float e = exp2f(d * 1.44269504f);
        ssum += e; sdot += e * d;
    }
    const float lns = logf(ssum);
    const float lse = mx + lns;
    const float entropy = lns - sdot / ssum;
    const int a = action[row];
    float la = 0.f;
    #pragma unroll
    for (int n = 0; n < 10; ++n) la = (n == a) ? logits[n] : la;
    if (lane == 0) {
        out[row] = value;
        out[BT_ + row] = la - lse;
        out[2 * BT_ + row] = entropy;
    }
}

// ---------------------------------------------------------------------------
extern "C" void kernel_launch(void* const* d_in, const int* in_sizes, int n_in,
                              void* d_out, int out_size, void* d_ws, size_t ws_size,
                              hipStream_t stream)
{
    const float* obs    = (const float*)d_in[0];
    const int*   action = (const int*)d_in[1];
    const int*   masks  = (const int*)d_in[2];
    const float* h0     = (const float*)d_in[3];
    const float* W1     = (const float*)d_in[4];
    const float* b1     = (const float*)d_in[5];
    const float* Wih    = (const float*)d_in[6];
    const float* Whh    = (const float*)d_in[7];
    const float* bih    = (const float*)d_in[8];
    const float* bhh    = (const float*)d_in[9];
    const float* Wa     = (const float*)d_in[10];
    const float* ba     = (const float*)d_in[11];
    const float* Wc     = (const float*)d_in[12];
    const float* bc     = (const float*)d_in[13];
    float* out = (float*)d_out;

    char* p = (char*)d_ws;
    __half*   gx   = (__half*)p;    p += (size_t)BT_ * G_ * 2;      // 50.3 MB
    uint32_t* hs2  = (uint32_t*)p;  p += (size_t)BT_ * H_ * 2;      // 16.8 MB
    uint32_t* W1h  = (uint32_t*)p;  p += FEAT_ * OBS_ * 2;          // 131 KB
    uint32_t* Wihh = (uint32_t*)p;  p += G_ * FEAT_ * 2;            // 786 KB
    uint4*    WhhR = (uint4*)p;     p += 512 * 36 * 16;             // 295 KB
    uint4*    WhhL = (uint4*)p;     p += 12 * 512 * 16;             // 98 KB
    int*      queue= (int*)p;       p += B_ * 512 * 4;              // 131 KB
    int*      qctl = (int*)p;       p += 256;                       // [0]=tail

    // packs (pack_whh zeroes qctl) + segment queue build
    pack_half<<<(FEAT_ * OBS_ / 2 + 255) / 256, 256, 0, stream>>>(W1, W1h, FEAT_ * OBS_ / 2);
    pack_half<<<(G_ * FEAT_ / 2 + 255) / 256, 256, 0, stream>>>(Wih, Wihh, G_ * FEAT_ / 2);
    pack_whh<<<384, 256, 0, stream>>>(Whh, (uint32_t*)WhhR, (uint32_t*)WhhL, qctl);
    seg_build<<<B_, 512, 0, stream>>>(masks, queue, &qctl[0]);
    // gx = relu(obs@W1^T+b1) @ Wih^T + bih  -- fused, feat never leaves LDS
    fused_gemm<<<768, 512, 0, stream>>>(obs, (const __half*)W1h, (const __half*)Wihh, b1, bih, (uint32_t*)gx);
    // pre-pass: all h_prev==0 steps (elementwise, grid-stride)
    h0pre<<<2048, 256, 0, stream>>>(gx, bhh, masks, hs2);
    // MFMA slot-parallel recurrence (static slices, 2 barriers/iter, pre-pop)
    gru_mfma<<<256, 512, 0, stream>>>(gx, WhhR, WhhL, bhh, h0, queue, qctl, hs2);
    // heads
    heads_kernel<<<8192, 256, 0, stream>>>(hs2, Wa, ba, Wc, bc, action, out);
}

// Round 13
// 203.700 us; speedup vs baseline: 1.1729x; 1.1729x over previous
//
#include <hip/hip_runtime.h>
#include <hip/hip_fp16.h>
#include <stdint.h>

#define B_    64
#define T_    512
#define OBS_  128
#define FEAT_ 512
#define H_    256
#define G_    768
#define BT_   32768
#define NSLOT 16

typedef _Float16 f16x8 __attribute__((ext_vector_type(8)));
typedef float    f32x4 __attribute__((ext_vector_type(4)));

__device__ __forceinline__ uint32_t h2u(__half2 h){ union{ __half2 h; uint32_t u; } c; c.h = h; return c.u; }
__device__ __forceinline__ __half2 u2h(uint32_t u){ union{ uint32_t u; __half2 h; } c; c.u = u; return c.h; }

// swizzled LDS byte offset: [rows][8 chunks of 16B], chunk ^= row&7
__device__ __forceinline__ int sw(int r, int c) { return r * 128 + ((c ^ (r & 7)) << 4); }

__device__ __forceinline__ uint4 cvt8(float4 a, float4 b) {
    uint4 u;
    u.x = h2u(__floats2half2_rn(a.x, a.y));
    u.y = h2u(__floats2half2_rn(a.z, a.w));
    u.z = h2u(__floats2half2_rn(b.x, b.y));
    u.w = h2u(__floats2half2_rn(b.z, b.w));
    return u;
}

// ---------------------------------------------------------------------------
// Fused feat+gx GEMM v3: 2 blocks/CU (r12 geometry; r12 FAILED only because
// the LDS partition offsets were written in bytes on a __half* -- featL
// landed inside obsA panel 1 and BsS overlapped featL. Fixed: offsets in
// halves. obsA bytes [0,16K), featL [16K,32K), BsS [32K,64K). 64KB total.)
// m-tile 64 x n-slice 256, 8 waves (1x8): acc 48 regs -> fits the 128-reg
// budget of __launch_bounds__(512,4) -> 2 blocks/CU for latency hiding.
// ---------------------------------------------------------------------------
__global__ __launch_bounds__(512, 4)
void fused_gemm(const float* __restrict__ obs, const __half* __restrict__ W1h,
                const __half* __restrict__ Wihh, const float* __restrict__ b1,
                const float* __restrict__ bih, uint32_t* __restrict__ gxC)
{
    __shared__ __align__(16) __half smem[32768];   // 64KB
    __half* obsA  = smem;            // bytes [0, 16384): 2 panels of 8KB, swizzled
    __half* featL = smem + 8192;     // bytes [16384, 32768): 2 panels of 8KB
    __half* BsS   = smem + 16384;    // bytes [32768, 65536): stage1 16KB / stage2 32KB

    const int bid = blockIdx.x;
    const int m0 = (bid & 511) * 64;
    const int n0 = (bid >> 9) * 256;
    const int tid = threadIdx.x;
    const int lane = tid & 63, wn = tid >> 6;      // 8 waves, 1x8 (all share m)
    const int l15 = lane & 15, lq = lane >> 4;

    // ---- stage obs tile once (64 rows x K=128 fp32 -> fp16, 2 panels) ----
    {
        const int r = tid >> 3, cpair = (tid & 7) * 2;
        #pragma unroll
        for (int c = 0; c < 2; ++c) {
            const int cc = cpair + c;              // 16B chunk id 0..15
            const float* ap = obs + (size_t)(m0 + r) * OBS_ + cc * 8;
            const float4 f0 = ((const float4*)ap)[0];
            const float4 f1 = ((const float4*)ap)[1];
            *(uint4*)((char*)obsA + (cc >> 3) * 8192 + sw(r, cc & 7)) = cvt8(f0, f1);
        }
    }

    f32x4 acc2[4][2];
    #pragma unroll
    for (int i = 0; i < 4; ++i)
        #pragma unroll
        for (int jj = 0; jj < 2; ++jj) { const f32x4 z = {0.f,0.f,0.f,0.f}; acc2[i][jj] = z; }

    for (int j = 0; j < 4; ++j) {
        // ---- stage 1: feat_sub[64 x 128] = relu(obs @ W1^T + b1), K=128 ----
        f32x4 acc1[4];
        #pragma unroll
        for (int i = 0; i < 4; ++i) { const f32x4 z = {0.f,0.f,0.f,0.f}; acc1[i] = z; }
        #pragma unroll
        for (int kt = 0; kt < 2; ++kt) {
            __syncthreads();                       // Bs free (prev compute done)
            if (tid < 256) {                       // stage W1 tile 128x64 (16KB)
                const int sr = tid >> 1, scb = (tid & 1) * 4;
                const __half* bp = W1h + (size_t)(j * 128 + sr) * OBS_ + kt * 64 + scb * 8;
                #pragma unroll
                for (int c = 0; c < 4; ++c)
                    *(uint4*)((char*)BsS + sw(sr, scb + c)) = ((const uint4*)bp)[c];
            }
            __syncthreads();
            #pragma unroll
            for (int kc = 0; kc < 2; ++kc) {
                f16x8 af[4];
                #pragma unroll
                for (int mi = 0; mi < 4; ++mi)
                    af[mi] = *(const f16x8*)((const char*)obsA + kt * 8192 +
                                             sw(mi * 16 + l15, kc * 4 + lq));
                const f16x8 bf = *(const f16x8*)((const char*)BsS +
                                                 sw(wn * 16 + l15, kc * 4 + lq));
                #pragma unroll
                for (int mi = 0; mi < 4; ++mi)
                    acc1[mi] = __builtin_amdgcn_mfma_f32_16x16x32_f16(af[mi], bf, acc1[mi], 0, 0, 0);
            }
        }
        // ---- feat_sub -> featL (bias+relu, fp16, A-operand layout) ----
        {
            const int col = wn * 16 + l15;         // feat col within j-chunk, 0..127
            const float bv = b1[j * 128 + col];
            #pragma unroll
            for (int mi = 0; mi < 4; ++mi) {
                const f32x4 d = acc1[mi];
                #pragma unroll
                for (int rr = 0; rr < 4; ++rr) {
                    const float v = fmaxf(d[rr] + bv, 0.0f);
                    const uint32_t u = (uint32_t)__half_as_ushort(__float2half(v));
                    const uint32_t nb = (uint32_t)__shfl_xor((int)u, 1);
                    if (!(lane & 1)) {
                        const int row = mi * 16 + lq * 4 + rr;   // 0..63
                        *(uint32_t*)((char*)featL + (col >> 6) * 8192 + row * 128 +
                                     ((((col >> 3) & 7) ^ (row & 7)) << 4) + (col & 7) * 2) = u | (nb << 16);
                    }
                }
            }
        }
        // ---- stage 2: gx_acc += feat_sub @ Wih^T (two BK=64 chunks) ----
        #pragma unroll
        for (int kt2 = 0; kt2 < 2; ++kt2) {
            __syncthreads();                       // featL visible; Bs free
            {                                      // stage Wih tile 256x64 (32KB)
                const int sr = tid >> 1, scb = (tid & 1) * 4;
                const __half* bp = Wihh + (size_t)(n0 + sr) * FEAT_ + j * 128 + kt2 * 64 + scb * 8;
                #pragma unroll
                for (int c = 0; c < 4; ++c)
                    *(uint4*)((char*)BsS + sw(sr, scb + c)) = ((const uint4*)bp)[c];
            }
            __syncthreads();
            #pragma unroll
            for (int kc = 0; kc < 2; ++kc) {
                f16x8 af[4], bf[2];
                #pragma unroll
                for (int mi = 0; mi < 4; ++mi)
                    af[mi] = *(const f16x8*)((const char*)featL + kt2 * 8192 +
                                             sw(mi * 16 + l15, kc * 4 + lq));
                #pragma unroll
                for (int ni = 0; ni < 2; ++ni)
                    bf[ni] = *(const f16x8*)((const char*)BsS +
                                             sw(wn * 32 + ni * 16 + l15, kc * 4 + lq));
                #pragma unroll
                for (int mi = 0; mi < 4; ++mi)
                    #pragma unroll
                    for (int ni = 0; ni < 2; ++ni)
                        acc2[mi][ni] = __builtin_amdgcn_mfma_f32_16x16x32_f16(af[mi], bf[ni], acc2[mi][ni], 0, 0, 0);
            }
        }
    }

    // ---- epilogue: Cs staging (32KB, reuses smem), 512B-contiguous rows ----
    __syncthreads();
    uint32_t* Cs = (uint32_t*)smem;                // [64][128] uint32 = 32KB
    #pragma unroll
    for (int ni = 0; ni < 2; ++ni) {
        const int col = wn * 32 + ni * 16 + l15;   // 0..255
        const float bv = bih[n0 + col];
        #pragma unroll
        for (int mi = 0; mi < 4; ++mi) {
            const f32x4 d = acc2[mi][ni];
            #pragma unroll
            for (int rr = 0; rr < 4; ++rr) {
                const float v = d[rr] + bv;
                const uint32_t u = (uint32_t)__half_as_ushort(__float2half(v));
                const uint32_t nb = (uint32_t)__shfl_xor((int)u, 1);
                if (!(lane & 1))
                    Cs[(mi * 16 + lq * 4 + rr) * 128 + (col >> 1)] = u | (nb << 16);
            }
        }
    }
    __syncthreads();
    const int orow = tid >> 3, oseg = (tid & 7) * 16;   // 8 thr x 64B per row
    #pragma unroll
    for (int c = 0; c < 4; ++c) {
        const uint4 val = *(const uint4*)&Cs[orow * 128 + oseg + c * 4];
        *(uint4*)(gxC + (size_t)(m0 + orow) * (G_ / 2) + (n0 >> 1) + oseg + c * 4) = val;
    }
}

// ---------------------------------------------------------------------------
// Weight packs (unchanged -- passed r8-r11). pack_whh zeroes qctl and splits
// W_hh into WhhR (reg K-chunks 0..5) + WhhL (LDS K-chunks 6..7).
// ---------------------------------------------------------------------------
__global__ void pack_half(const float* __restrict__ in, uint32_t* __restrict__ out, int n2)
{
    int i = blockIdx.x * 256 + threadIdx.x;
    if (i < n2) {
        float2 f = ((const float2*)in)[i];
        out[i] = h2u(__floats2half2_rn(f.x, f.y));
    }
}

__global__ void pack_whh(const float* __restrict__ Whh, uint32_t* __restrict__ outR,
                         uint32_t* __restrict__ outL, int* __restrict__ qctl)
{
    if (blockIdx.x == 0 && threadIdx.x == 0) { qctl[0] = 0; qctl[1] = 0; }
    int p = blockIdx.x * 256 + threadIdx.x;
    if (p >= 512 * 192) return;
    const int v4 = p >> 2, sub = p & 3;
    const int t = v4 / 48, ic = v4 - t * 48;
    const int i = ic >> 3, c = ic & 7;
    const int w = t >> 6, lane = t & 63;
    const int row = w * 96 + i * 16 + (lane & 15);
    const int kb = c * 32 + ((lane >> 4) << 3) + sub * 2;
    const uint32_t val = h2u(__floats2half2_rn(Whh[row * 256 + kb], Whh[row * 256 + kb + 1]));
    if (c < 6) outR[(t * 36 + i * 6 + c) * 4 + sub] = val;
    else       outL[(((i << 1) + (c - 6)) * 512 + t) * 4 + sub] = val;
}

// ---------------------------------------------------------------------------
// Segment builder (unchanged -- passed r6/r8-r11).
// ---------------------------------------------------------------------------
__global__ __launch_bounds__(512)
void seg_build(const int* __restrict__ masks, int* __restrict__ queue,
               int* __restrict__ qtail)
{
    __shared__ int sc[512];
    __shared__ int starts[512];
    __shared__ int cshr[2];
    const int b = blockIdx.x, s = threadIdx.x;
    const int is = (s == 0) || (masks[b * (T_ - 1) + s - 1] == 0);
    sc[s] = is;
    __syncthreads();
    #pragma unroll
    for (int off = 1; off < 512; off <<= 1) {
        int v = (s >= off) ? sc[s - off] : 0;
        __syncthreads();
        sc[s] += v;
        __syncthreads();
    }
    if (is) starts[sc[s] - 1] = s;
    if (s == 511) cshr[0] = sc[511];
    __syncthreads();
    const int cnt = cshr[0];
    int valid = 0, st = 0, ln = 0;
    if (s < cnt) {
        st = starts[s];
        const int nxt = (s + 1 < cnt) ? starts[s + 1] : T_;
        ln = nxt - st;
        valid = (st == 0 || ln >= 2) ? 1 : 0;
    }
    sc[s] = valid;
    __syncthreads();
    #pragma unroll
    for (int off = 1; off < 512; off <<= 1) {
        int v = (s >= off) ? sc[s - off] : 0;
        __syncthreads();
        sc[s] += v;
        __syncthreads();
    }
    if (s == 511) cshr[1] = atomicAdd(qtail, sc[511]);
    __syncthreads();
    if (valid) queue[cshr[1] + sc[s] - 1] = (b << 19) | (st << 10) | ln;
}

// ---------------------------------------------------------------------------
// Pre-pass, grid-stride (unchanged -- passed r8-r11).
// ---------------------------------------------------------------------------
__global__ __launch_bounds__(256)
void h0pre(const __half* __restrict__ gx, const float* __restrict__ bhh,
           const int* __restrict__ masks, uint32_t* __restrict__ hs2)
{
    for (int row = blockIdx.x; row < B_ * (T_ - 1); row += gridDim.x) {
        if (masks[row] != 0) continue;
        const int b = row / (T_ - 1), t = 1 + row - b * (T_ - 1);
        const int e = threadIdx.x;
        const __half* grow = gx + (size_t)(b * T_ + t) * 768;
        const float gxr = __half2float(grow[e]);
        const float gxz = __half2float(grow[e + 256]);
        const float gxn = __half2float(grow[e + 512]);
        const float rg = 1.f / (1.f + exp2f(-(gxr + bhh[e]) * 1.44269504f));
        const float zg = 1.f / (1.f + exp2f(-(gxz + bhh[e + 256]) * 1.44269504f));
        const float nin = gxn + rg * bhh[e + 512];
        const float e2x = exp2f(nin * 2.885390082f);
        const float ng = 1.f - 2.f / (e2x + 1.f);
        const float hnew = (1.f - zg) * ng;     // h_prev = 0
        const float other = __shfl_xor(hnew, 1);
        if (!(e & 1)) hs2[(size_t)(b * T_ + t) * 128 + (e >> 1)] = h2u(__floats2half2_rn(hnew, other));
    }
}

// ---------------------------------------------------------------------------
// MFMA slot-parallel GRU v3 (unchanged -- passed r8-r11).
// ---------------------------------------------------------------------------
__global__ __launch_bounds__(512, 2)
void gru_mfma(const __half* __restrict__ gx, const uint4* __restrict__ WhhR,
              const uint4* __restrict__ WhhL, const float* __restrict__ bhh,
              const float* __restrict__ h0, const int* __restrict__ queue,
              const int* __restrict__ qctl, uint32_t* __restrict__ hs2)
{
    __shared__ __align__(16) __half Hl[NSLOT * 256];   // 8KB, granule-swizzled
    __shared__ __align__(16) __half Plh[NSLOT * 784];  // 24.5KB gh (fp16)
    __shared__ __align__(16) uint4  Wl[12 * 512];      // 98KB W_hh K-chunks 6..7
    __shared__ float Bl[G_];
    __shared__ int s_end[NSLOT], s_row[NSLOT], s_act[NSLOT], s_nxt[NSLOT];
    __shared__ int cur;

    const int tid = threadIdx.x;
    const int lane = tid & 63, w = tid >> 6;
    const int s = tid >> 5, g32 = tid & 31, e0 = g32 * 8;
    const int col = lane & 15, lq = lane >> 4;

    f16x8 wr[36];
    {
        const f16x8* wp = (const f16x8*)(WhhR + (size_t)tid * 36);
        #pragma unroll
        for (int i = 0; i < 36; ++i) wr[i] = wp[i];
    }
    #pragma unroll
    for (int i = 0; i < 12; ++i) Wl[i * 512 + tid] = WhhL[i * 512 + tid];
    if (tid < 384) { Bl[tid] = bhh[tid]; Bl[tid + 384] = bhh[tid + 384]; }
    { const uint4 z4 = {0u, 0u, 0u, 0u}; *(uint4*)((char*)Hl + tid * 16) = z4; }

    const int NQ = qctl[0];
    const int gb = blockIdx.x;
    const int lo = (int)(((long long)NQ * gb) >> 8);
    const int hi = (int)(((long long)NQ * (gb + 1)) >> 8);
    if (tid == 0) cur = lo + NSLOT;
    __syncthreads();

    {
        int e = -1;
        if (lo + s < hi) e = queue[lo + s];
        if (e >= 0) {
            const int ln = e & 1023, st = (e >> 10) & 511, nb = e >> 19;
            uint4 hseed;
            if (st == 0) {
                const float4 a = *(const float4*)(h0 + nb * 256 + e0);
                const float4 b = *(const float4*)(h0 + nb * 256 + e0 + 4);
                hseed = cvt8(a, b);
                if (g32 == 0) { s_row[s] = nb * T_; s_end[s] = nb * T_ + ln; }
            } else {
                hseed = *(const uint4*)(hs2 + (size_t)(nb * T_ + st) * 128 + g32 * 4);
                if (g32 == 0) { s_row[s] = nb * T_ + st + 1; s_end[s] = nb * T_ + st + ln; }
            }
            *(uint4*)((char*)Hl + s * 512 + ((g32 ^ (s & 7)) << 4)) = hseed;
            if (g32 == 0) {
                s_act[s] = 1;
                const int p = atomicAdd(&cur, 1);
                s_nxt[s] = (p < hi) ? queue[p] : -1;
            }
        } else if (g32 == 0) {
            s_act[s] = 0; s_nxt[s] = -1; s_row[s] = 0; s_end[s] = 0;
        }
    }
    __syncthreads();

    for (;;) {
        bool alive = false;
        #pragma unroll
        for (int i = 0; i < NSLOT; ++i) alive |= (s_act[i] != 0);
        if (!alive) break;

        // ---- phase X ----
        const int myrow = s_row[s];
        const int nxte = s_nxt[s];
        const __half* grow = gx + (size_t)myrow * G_;
        const f16x8 gr = *(const f16x8*)(grow + e0);
        const f16x8 gz = *(const f16x8*)(grow + 256 + e0);
        const f16x8 gn = *(const f16x8*)(grow + 512 + e0);
        uint4 su = {0u, 0u, 0u, 0u};
        if (nxte >= 0) {
            const int st = (nxte >> 10) & 511, nb = nxte >> 19;
            if (st == 0) {
                const float4 a = *(const float4*)(h0 + nb * 256 + e0);
                const float4 b = *(const float4*)(h0 + nb * 256 + e0 + 4);
                su = cvt8(a, b);
            } else {
                su = *(const uint4*)(hs2 + (size_t)(nb * T_ + st) * 128 + g32 * 4);
            }
        }
        f16x8 bfv[8];
        #pragma unroll
        for (int c = 0; c < 8; ++c)
            bfv[c] = *(const f16x8*)((const char*)Hl + col * 512 +
                                     ((((c << 2) + lq) ^ (col & 7)) << 4));
        f32x4 acc[6];
        #pragma unroll
        for (int i = 0; i < 6; ++i) { const f32x4 z = {0.f, 0.f, 0.f, 0.f}; acc[i] = z; }
        #pragma unroll
        for (int c = 0; c < 6; ++c)
            #pragma unroll
            for (int i = 0; i < 6; ++i)
                acc[i] = __builtin_amdgcn_mfma_f32_16x16x32_f16(wr[i * 6 + c], bfv[c], acc[i], 0, 0, 0);
        #pragma unroll
        for (int c2 = 0; c2 < 2; ++c2)
            #pragma unroll
            for (int i = 0; i < 6; ++i) {
                const f16x8 wlt = *(const f16x8*)&Wl[(i * 2 + c2) * 512 + tid];
                acc[i] = __builtin_amdgcn_mfma_f32_16x16x32_f16(wlt, bfv[6 + c2], acc[i], 0, 0, 0);
            }
        #pragma unroll
        for (int i = 0; i < 6; ++i) {
            uint2 ph;
            ph.x = h2u(__floats2half2_rn(acc[i][0], acc[i][1]));
            ph.y = h2u(__floats2half2_rn(acc[i][2], acc[i][3]));
            *(uint2*)(Plh + col * 784 + (w * 96 + i * 16 + lq * 4)) = ph;
        }
        asm volatile("s_waitcnt lgkmcnt(0)" ::: "memory");
        __builtin_amdgcn_s_barrier();

        // ---- phase Y ----
        if (s_act[s]) {
            const __half* Pr = Plh + s * 784;
            const f16x8 R  = *(const f16x8*)(Pr + e0);
            const f16x8 Z  = *(const f16x8*)(Pr + 256 + e0);
            const f16x8 Nn = *(const f16x8*)(Pr + 512 + e0);
            const f32x4 br0 = *(const f32x4*)(Bl + e0),       br1 = *(const f32x4*)(Bl + e0 + 4);
            const f32x4 bz0 = *(const f32x4*)(Bl + 256 + e0), bz1 = *(const f32x4*)(Bl + 256 + e0 + 4);
            const f32x4 bn0 = *(const f32x4*)(Bl + 512 + e0), bn1 = *(const f32x4*)(Bl + 512 + e0 + 4);
            const uint4 hp4 = *(const uint4*)((const char*)Hl + s * 512 + ((g32 ^ (s & 7)) << 4));
            const __half2 q0 = u2h(hp4.x), q1 = u2h(hp4.y), q2 = u2h(hp4.z), q3 = u2h(hp4.w);
            const float hpv[8] = { __low2float(q0), __high2float(q0), __low2float(q1), __high2float(q1),
                                   __low2float(q2), __high2float(q2), __low2float(q3), __high2float(q3) };
            float hn[8];
            #pragma unroll
            for (int j = 0; j < 8; ++j) {
                const float ghr = (float)R[j]  + (j < 4 ? br0[j] : br1[j - 4]);
                const float ghz = (float)Z[j]  + (j < 4 ? bz0[j] : bz1[j - 4]);
                const float ghn = (float)Nn[j] + (j < 4 ? bn0[j] : bn1[j - 4]);
                const float rg = 1.f / (1.f + exp2f(-((float)gr[j] + ghr) * 1.44269504f));
                const float zg = 1.f / (1.f + exp2f(-((float)gz[j] + ghz) * 1.44269504f));
                const float nin = (float)gn[j] + rg * ghn;
                const float ex = exp2f(nin * 2.885390082f);
                const float ng = 1.f - 2.f / (ex + 1.f);
                hn[j] = (1.f - zg) * ng + zg * hpv[j];
            }
            uint4 hp;
            hp.x = h2u(__floats2half2_rn(hn[0], hn[1]));
            hp.y = h2u(__floats2half2_rn(hn[2], hn[3]));
            hp.z = h2u(__floats2half2_rn(hn[4], hn[5]));
            hp.w = h2u(__floats2half2_rn(hn[6], hn[7]));
            *(uint4*)(hs2 + (size_t)myrow * 128 + g32 * 4) = hp;
            if (myrow + 1 < s_end[s]) {
                *(uint4*)((char*)Hl + s * 512 + ((g32 ^ (s & 7)) << 4)) = hp;
                if (g32 == 0) s_row[s] = myrow + 1;
            } else if (nxte >= 0) {
                const int ln = nxte & 1023, st = (nxte >> 10) & 511, nb = nxte >> 19;
                *(uint4*)((char*)Hl + s * 512 + ((g32 ^ (s & 7)) << 4)) = su;
                if (g32 == 0) {
                    if (st == 0) { s_row[s] = nb * T_;          s_end[s] = nb * T_ + ln; }
                    else         { s_row[s] = nb * T_ + st + 1; s_end[s] = nb * T_ + st + ln; }
                    const int p = atomicAdd(&cur, 1);
                    s_nxt[s] = (p < hi) ? queue[p] : -1;
                }
            } else if (g32 == 0) {
                s_act[s] = 0;
            }
        }
        asm volatile("s_waitcnt lgkmcnt(0)" ::: "memory");
        __builtin_amdgcn_s_barrier();
    }
}

// ---------------------------------------------------------------------------
// Heads (unchanged, passed): one wave per output row, hs fp16.
// ---------------------------------------------------------------------------
__global__ __launch_bounds__(256)
void heads_kernel(const uint32_t* __restrict__ hs2, const float* __restrict__ Wa,
                  const float* __restrict__ ba, const float* __restrict__ Wc,
                  const float* __restrict__ bc, const int* __restrict__ action,
                  float* __restrict__ out)
{
    const int wid = threadIdx.x >> 6, lane = threadIdx.x & 63;
    const int row = blockIdx.x * 4 + wid;
    const uint2 hv2 = ((const uint2*)(hs2 + (size_t)row * 128))[lane];
    const __half2 ha = u2h(hv2.x), hb = u2h(hv2.y);
    const float h0f = __low2float(ha), h1f = __high2float(ha);
    const float h2f = __low2float(hb), h3f = __high2float(hb);
    float sums[11];
    #pragma unroll
    for (int n = 0; n < 11; ++n) {
        const float* wrow = (n < 10) ? (Wa + n * 256) : Wc;
        const float4 wv = ((const float4*)wrow)[lane];
        sums[n] = h0f * wv.x + h1f * wv.y + h2f * wv.z + h3f * wv.w;
    }
    #pragma unroll
    for (int n = 0; n < 11; ++n) {
        float v = sums[n];
        #pragma unroll
        for (int off = 32; off; off >>= 1) v += __shfl_xor(v, off);
        sums[n] = v;
    }
    float logits[10];
    #pragma unroll
    for (int n = 0; n < 10; ++n) logits[n] = sums[n] + ba[n];
    const float value = sums[10] + bc[0];
    float mx = logits[0];
    #pragma unroll
    for (int n = 1; n < 10; ++n) mx = fmaxf(mx, logits[n]);
    float ssum = 0.f, sdot = 0.f;
    #pragma unroll
    for (int n = 0; n < 10; ++n) {
        float d = logits[n] - mx;
        float e = exp2f(d * 1.44269504f);
        ssum += e; sdot += e * d;
    }
    const float lns = logf(ssum);
    const float lse = mx + lns;
    const float entropy = lns - sdot / ssum;
    const int a = action[row];
    float la = 0.f;
    #pragma unroll
    for (int n = 0; n < 10; ++n) la = (n == a) ? logits[n] : la;
    if (lane == 0) {
        out[row] = value;
        out[BT_ + row] = la - lse;
        out[2 * BT_ + row] = entropy;
    }
}

// ---------------------------------------------------------------------------
extern "C" void kernel_launch(void* const* d_in, const int* in_sizes, int n_in,
                              void* d_out, int out_size, void* d_ws, size_t ws_size,
                              hipStream_t stream)
{
    const float* obs    = (const float*)d_in[0];
    const int*   action = (const int*)d_in[1];
    const int*   masks  = (const int*)d_in[2];
    const float* h0     = (const float*)d_in[3];
    const float* W1     = (const float*)d_in[4];
    const float* b1     = (const float*)d_in[5];
    const float* Wih    = (const float*)d_in[6];
    const float* Whh    = (const float*)d_in[7];
    const float* bih    = (const float*)d_in[8];
    const float* bhh    = (const float*)d_in[9];
    const float* Wa     = (const float*)d_in[10];
    const float* ba     = (const float*)d_in[11];
    const float* Wc     = (const float*)d_in[12];
    const float* bc     = (const float*)d_in[13];
    float* out = (float*)d_out;

    char* p = (char*)d_ws;
    __half*   gx   = (__half*)p;    p += (size_t)BT_ * G_ * 2;      // 50.3 MB
    uint32_t* hs2  = (uint32_t*)p;  p += (size_t)BT_ * H_ * 2;      // 16.8 MB
    uint32_t* W1h  = (uint32_t*)p;  p += FEAT_ * OBS_ * 2;          // 131 KB
    uint32_t* Wihh = (uint32_t*)p;  p += G_ * FEAT_ * 2;            // 786 KB
    uint4*    WhhR = (uint4*)p;     p += 512 * 36 * 16;             // 295 KB
    uint4*    WhhL = (uint4*)p;     p += 12 * 512 * 16;             // 98 KB
    int*      queue= (int*)p;       p += B_ * 512 * 4;              // 131 KB
    int*      qctl = (int*)p;       p += 256;                       // [0]=tail

    // packs (pack_whh zeroes qctl) + segment queue build
    pack_half<<<(FEAT_ * OBS_ / 2 + 255) / 256, 256, 0, stream>>>(W1, W1h, FEAT_ * OBS_ / 2);
    pack_half<<<(G_ * FEAT_ / 2 + 255) / 256, 256, 0, stream>>>(Wih, Wihh, G_ * FEAT_ / 2);
    pack_whh<<<384, 256, 0, stream>>>(Whh, (uint32_t*)WhhR, (uint32_t*)WhhL, qctl);
    seg_build<<<B_, 512, 0, stream>>>(masks, queue, &qctl[0]);
    // gx = relu(obs@W1^T+b1) @ Wih^T + bih  -- fused, feat never leaves LDS
    fused_gemm<<<1536, 512, 0, stream>>>(obs, (const __half*)W1h, (const __half*)Wihh, b1, bih, (uint32_t*)gx);
    // pre-pass: all h_prev==0 steps (elementwise, grid-stride)
    h0pre<<<2048, 256, 0, stream>>>(gx, bhh, masks, hs2);
    // MFMA slot-parallel recurrence (static slices, 2 barriers/iter, pre-pop)
    gru_mfma<<<256, 512, 0, stream>>>(gx, WhhR, WhhL, bhh, h0, queue, qctl, hs2);
    // heads
    heads_kernel<<<8192, 256, 0, stream>>>(hs2, Wa, ba, Wc, bc, action, out);
}

// Round 14
// 177.466 us; speedup vs baseline: 1.3463x; 1.1478x over previous
//
#include <hip/hip_runtime.h>
#include <hip/hip_fp16.h>
#include <stdint.h>

#define B_    64
#define T_    512
#define OBS_  128
#define FEAT_ 512
#define H_    256
#define G_    768
#define BT_   32768
#define NSLOT 16

typedef _Float16 f16x8 __attribute__((ext_vector_type(8)));
typedef float    f32x4 __attribute__((ext_vector_type(4)));

__device__ __forceinline__ uint32_t h2u(__half2 h){ union{ __half2 h; uint32_t u; } c; c.h = h; return c.u; }
__device__ __forceinline__ __half2 u2h(uint32_t u){ union{ uint32_t u; __half2 h; } c; c.u = u; return c.h; }

// swizzled LDS byte offset: [rows][8 chunks of 16B], chunk ^= row&7
__device__ __forceinline__ int sw(int r, int c) { return r * 128 + ((c ^ (r & 7)) << 4); }

__device__ __forceinline__ uint4 cvt8(float4 a, float4 b) {
    uint4 u;
    u.x = h2u(__floats2half2_rn(a.x, a.y));
    u.y = h2u(__floats2half2_rn(a.z, a.w));
    u.z = h2u(__floats2half2_rn(b.x, b.y));
    u.w = h2u(__floats2half2_rn(b.z, b.w));
    return u;
}

// ---------------------------------------------------------------------------
// Fused feat+gx GEMM v4: B-operands live in REGISTERS (no W LDS staging).
// r13 counters (MfmaUtil 16%, 16 staging-barrier pairs with exposed W loads)
// showed the W-tile LDS round-trip was the schedule bottleneck. W1/Wih are
// pre-packed in MFMA B-fragment order (pack_bfrag): fragment f for col-tile
// ct, 32-k-chunk k32 is 64 lanes x 16B contiguous -> one dwordx4 per lane,
// L2-resident. Barriers drop 32 -> 8 per block (featL handoff only).
// Geometry unchanged from r13 (passed): m-tile 64 x n 256, 8 waves, grid
// 1536 = 512m x 3n, 2 blocks/CU. LDS 32KB (obsA 16 | featL 16; Cs reuses).
// ---------------------------------------------------------------------------
__global__ __launch_bounds__(512, 4)
void fused_gemm(const float* __restrict__ obs, const uint4* __restrict__ W1f,
                const uint4* __restrict__ Wihf, const float* __restrict__ b1,
                const float* __restrict__ bih, uint32_t* __restrict__ gxC)
{
    __shared__ __align__(16) __half smem[16384];   // 32KB
    __half* obsA  = smem;            // bytes [0, 16384): 2 panels of 8KB, swizzled
    __half* featL = smem + 8192;     // bytes [16384, 32768): 2 panels of 8KB

    const int bid = blockIdx.x;
    const int m0 = (bid & 511) * 64;
    const int nt = bid >> 9;                       // 0..2
    const int tid = threadIdx.x;
    const int lane = tid & 63, wn = tid >> 6;      // 8 waves, 1x8
    const int l15 = lane & 15, lq = lane >> 4;

    // ---- stage obs tile once (64 rows x K=128 fp32 -> fp16, 2 panels) ----
    {
        const int r = tid >> 3, cpair = (tid & 7) * 2;
        #pragma unroll
        for (int c = 0; c < 2; ++c) {
            const int cc = cpair + c;
            const float* ap = obs + (size_t)(m0 + r) * OBS_ + cc * 8;
            const float4 f0 = ((const float4*)ap)[0];
            const float4 f1 = ((const float4*)ap)[1];
            *(uint4*)((char*)obsA + (cc >> 3) * 8192 + sw(r, cc & 7)) = cvt8(f0, f1);
        }
    }
    __syncthreads();

    f32x4 acc2[4][2];
    #pragma unroll
    for (int i = 0; i < 4; ++i)
        #pragma unroll
        for (int jj = 0; jj < 2; ++jj) { const f32x4 z = {0.f,0.f,0.f,0.f}; acc2[i][jj] = z; }

    for (int j = 0; j < 4; ++j) {
        // ---- W1 frags for this j (4 x dwordx4/lane, L2): ct1 = j*8+wn ----
        uint4 w1f[4];
        {
            const uint4* base = W1f + ((size_t)(j * 8 + wn) * 4) * 64 + lane;
            #pragma unroll
            for (int q = 0; q < 4; ++q) w1f[q] = base[q * 64];
        }
        // ---- Wih frags kt2=0 (in flight across stage1) ----
        uint4 wif0[4];
        #pragma unroll
        for (int ni = 0; ni < 2; ++ni) {
            const uint4* base = Wihf + ((size_t)(nt * 16 + wn * 2 + ni) * 16 + j * 4) * 64 + lane;
            #pragma unroll
            for (int kc = 0; kc < 2; ++kc) wif0[ni * 2 + kc] = base[kc * 64];
        }
        // ---- stage 1: feat_sub[64x128] = relu(obs @ W1^T + b1) ----
        f32x4 acc1[4];
        #pragma unroll
        for (int i = 0; i < 4; ++i) { const f32x4 z = {0.f,0.f,0.f,0.f}; acc1[i] = z; }
        #pragma unroll
        for (int kt = 0; kt < 2; ++kt)
            #pragma unroll
            for (int kc = 0; kc < 2; ++kc) {
                f16x8 af[4];
                #pragma unroll
                for (int mi = 0; mi < 4; ++mi)
                    af[mi] = *(const f16x8*)((const char*)obsA + kt * 8192 +
                                             sw(mi * 16 + l15, kc * 4 + lq));
                const f16x8 bf = *(const f16x8*)&w1f[kt * 2 + kc];
                #pragma unroll
                for (int mi = 0; mi < 4; ++mi)
                    acc1[mi] = __builtin_amdgcn_mfma_f32_16x16x32_f16(af[mi], bf, acc1[mi], 0, 0, 0);
            }
        // ---- feat_sub -> featL (bias+relu, fp16, A-operand layout) ----
        {
            const int col = wn * 16 + l15;         // 0..127 within j-chunk
            const float bv = b1[j * 128 + col];
            #pragma unroll
            for (int mi = 0; mi < 4; ++mi) {
                const f32x4 d = acc1[mi];
                #pragma unroll
                for (int rr = 0; rr < 4; ++rr) {
                    const float v = fmaxf(d[rr] + bv, 0.0f);
                    const uint32_t u = (uint32_t)__half_as_ushort(__float2half(v));
                    const uint32_t nb = (uint32_t)__shfl_xor((int)u, 1);
                    if (!(lane & 1)) {
                        const int row = mi * 16 + lq * 4 + rr;   // 0..63
                        *(uint32_t*)((char*)featL + (col >> 6) * 8192 + row * 128 +
                                     ((((col >> 3) & 7) ^ (row & 7)) << 4) + (col & 7) * 2) = u | (nb << 16);
                    }
                }
            }
        }
        __syncthreads();                           // featL visible
        // ---- Wih frags kt2=1 (in flight across kt2=0 compute) ----
        uint4 wif1[4];
        #pragma unroll
        for (int ni = 0; ni < 2; ++ni) {
            const uint4* base = Wihf + ((size_t)(nt * 16 + wn * 2 + ni) * 16 + j * 4 + 2) * 64 + lane;
            #pragma unroll
            for (int kc = 0; kc < 2; ++kc) wif1[ni * 2 + kc] = base[kc * 64];
        }
        // ---- stage 2: gx_acc += feat_sub @ Wih^T (kt2 = 0 then 1) ----
        #pragma unroll
        for (int kc = 0; kc < 2; ++kc) {
            f16x8 af[4];
            #pragma unroll
            for (int mi = 0; mi < 4; ++mi)
                af[mi] = *(const f16x8*)((const char*)featL +
                                         sw(mi * 16 + l15, kc * 4 + lq));
            #pragma unroll
            for (int ni = 0; ni < 2; ++ni) {
                const f16x8 bf = *(const f16x8*)&wif0[ni * 2 + kc];
                #pragma unroll
                for (int mi = 0; mi < 4; ++mi)
                    acc2[mi][ni] = __builtin_amdgcn_mfma_f32_16x16x32_f16(af[mi], bf, acc2[mi][ni], 0, 0, 0);
            }
        }
        #pragma unroll
        for (int kc = 0; kc < 2; ++kc) {
            f16x8 af[4];
            #pragma unroll
            for (int mi = 0; mi < 4; ++mi)
                af[mi] = *(const f16x8*)((const char*)featL + 8192 +
                                         sw(mi * 16 + l15, kc * 4 + lq));
            #pragma unroll
            for (int ni = 0; ni < 2; ++ni) {
                const f16x8 bf = *(const f16x8*)&wif1[ni * 2 + kc];
                #pragma unroll
                for (int mi = 0; mi < 4; ++mi)
                    acc2[mi][ni] = __builtin_amdgcn_mfma_f32_16x16x32_f16(af[mi], bf, acc2[mi][ni], 0, 0, 0);
            }
        }
        __syncthreads();                           // featL free for next j
    }

    // ---- epilogue: Cs staging (32KB, reuses smem), contiguous row writes ----
    uint32_t* Cs = (uint32_t*)smem;                // [64][128] uint32 = 32KB
    #pragma unroll
    for (int ni = 0; ni < 2; ++ni) {
        const int col = wn * 32 + ni * 16 + l15;   // 0..255
        const float bv = bih[nt * 256 + col];
        #pragma unroll
        for (int mi = 0; mi < 4; ++mi) {
            const f32x4 d = acc2[mi][ni];
            #pragma unroll
            for (int rr = 0; rr < 4; ++rr) {
                const float v = d[rr] + bv;
                const uint32_t u = (uint32_t)__half_as_ushort(__float2half(v));
                const uint32_t nb = (uint32_t)__shfl_xor((int)u, 1);
                if (!(lane & 1))
                    Cs[(mi * 16 + lq * 4 + rr) * 128 + (col >> 1)] = u | (nb << 16);
            }
        }
    }
    __syncthreads();
    const int orow = tid >> 3, oseg = (tid & 7) * 16;   // 8 thr x 64B per row
    #pragma unroll
    for (int c = 0; c < 4; ++c) {
        const uint4 val = *(const uint4*)&Cs[orow * 128 + oseg + c * 4];
        *(uint4*)(gxC + (size_t)(m0 + orow) * (G_ / 2) + (nt * 128) + oseg + c * 4) = val;
    }
}

// ---------------------------------------------------------------------------
// Weight packs. pack_bfrag: W[N x K] fp32 -> MFMA B-fragment order:
// out u32 p = (f*64 + l)*4 + e2, f = ct*(K/32) + k32,
// value = half2(W[ct*16 + (l&15)][k32*32 + (l>>4)*8 + e2*2], ..+1).
// Derived from the r13-proven BsS read address algebra (same as pack_whh).
// ---------------------------------------------------------------------------
template<int K>
__global__ void pack_bfrag(const float* __restrict__ W, uint32_t* __restrict__ out, int total)
{
    int p = blockIdx.x * 256 + threadIdx.x;
    if (p >= total) return;
    const int e2 = p & 3;
    const int l  = (p >> 2) & 63;
    const int f  = p >> 8;
    const int k32 = f & (K / 32 - 1);
    const int ct  = f / (K / 32);
    const int row = ct * 16 + (l & 15);
    const int k   = k32 * 32 + ((l >> 4) << 3) + e2 * 2;
    out[p] = h2u(__floats2half2_rn(W[(size_t)row * K + k], W[(size_t)row * K + k + 1]));
}

__global__ void pack_whh(const float* __restrict__ Whh, uint32_t* __restrict__ outR,
                         uint32_t* __restrict__ outL, int* __restrict__ qctl)
{
    if (blockIdx.x == 0 && threadIdx.x == 0) { qctl[0] = 0; qctl[1] = 0; }
    int p = blockIdx.x * 256 + threadIdx.x;
    if (p >= 512 * 192) return;
    const int v4 = p >> 2, sub = p & 3;
    const int t = v4 / 48, ic = v4 - t * 48;
    const int i = ic >> 3, c = ic & 7;
    const int w = t >> 6, lane = t & 63;
    const int row = w * 96 + i * 16 + (lane & 15);
    const int kb = c * 32 + ((lane >> 4) << 3) + sub * 2;
    const uint32_t val = h2u(__floats2half2_rn(Whh[row * 256 + kb], Whh[row * 256 + kb + 1]));
    if (c < 6) outR[(t * 36 + i * 6 + c) * 4 + sub] = val;
    else       outL[(((i << 1) + (c - 6)) * 512 + t) * 4 + sub] = val;
}

// ---------------------------------------------------------------------------
// Segment builder (unchanged -- passed r6/r8-r13).
// ---------------------------------------------------------------------------
__global__ __launch_bounds__(512)
void seg_build(const int* __restrict__ masks, int* __restrict__ queue,
               int* __restrict__ qtail)
{
    __shared__ int sc[512];
    __shared__ int starts[512];
    __shared__ int cshr[2];
    const int b = blockIdx.x, s = threadIdx.x;
    const int is = (s == 0) || (masks[b * (T_ - 1) + s - 1] == 0);
    sc[s] = is;
    __syncthreads();
    #pragma unroll
    for (int off = 1; off < 512; off <<= 1) {
        int v = (s >= off) ? sc[s - off] : 0;
        __syncthreads();
        sc[s] += v;
        __syncthreads();
    }
    if (is) starts[sc[s] - 1] = s;
    if (s == 511) cshr[0] = sc[511];
    __syncthreads();
    const int cnt = cshr[0];
    int valid = 0, st = 0, ln = 0;
    if (s < cnt) {
        st = starts[s];
        const int nxt = (s + 1 < cnt) ? starts[s + 1] : T_;
        ln = nxt - st;
        valid = (st == 0 || ln >= 2) ? 1 : 0;
    }
    sc[s] = valid;
    __syncthreads();
    #pragma unroll
    for (int off = 1; off < 512; off <<= 1) {
        int v = (s >= off) ? sc[s - off] : 0;
        __syncthreads();
        sc[s] += v;
        __syncthreads();
    }
    if (s == 511) cshr[1] = atomicAdd(qtail, sc[511]);
    __syncthreads();
    if (valid) queue[cshr[1] + sc[s] - 1] = (b << 19) | (st << 10) | ln;
}

// ---------------------------------------------------------------------------
// Pre-pass, grid-stride (unchanged -- passed r8-r13).
// ---------------------------------------------------------------------------
__global__ __launch_bounds__(256)
void h0pre(const __half* __restrict__ gx, const float* __restrict__ bhh,
           const int* __restrict__ masks, uint32_t* __restrict__ hs2)
{
    for (int row = blockIdx.x; row < B_ * (T_ - 1); row += gridDim.x) {
        if (masks[row] != 0) continue;
        const int b = row / (T_ - 1), t = 1 + row - b * (T_ - 1);
        const int e = threadIdx.x;
        const __half* grow = gx + (size_t)(b * T_ + t) * 768;
        const float gxr = __half2float(grow[e]);
        const float gxz = __half2float(grow[e + 256]);
        const float gxn = __half2float(grow[e + 512]);
        const float rg = 1.f / (1.f + exp2f(-(gxr + bhh[e]) * 1.44269504f));
        const float zg = 1.f / (1.f + exp2f(-(gxz + bhh[e + 256]) * 1.44269504f));
        const float nin = gxn + rg * bhh[e + 512];
        const float e2x = exp2f(nin * 2.885390082f);
        const float ng = 1.f - 2.f / (e2x + 1.f);
        const float hnew = (1.f - zg) * ng;     // h_prev = 0
        const float other = __shfl_xor(hnew, 1);
        if (!(e & 1)) hs2[(size_t)(b * T_ + t) * 128 + (e >> 1)] = h2u(__floats2half2_rn(hnew, other));
    }
}

// ---------------------------------------------------------------------------
// MFMA slot-parallel GRU v3 (unchanged -- passed r8-r13).
// ---------------------------------------------------------------------------
__global__ __launch_bounds__(512, 2)
void gru_mfma(const __half* __restrict__ gx, const uint4* __restrict__ WhhR,
              const uint4* __restrict__ WhhL, const float* __restrict__ bhh,
              const float* __restrict__ h0, const int* __restrict__ queue,
              const int* __restrict__ qctl, uint32_t* __restrict__ hs2)
{
    __shared__ __align__(16) __half Hl[NSLOT * 256];   // 8KB, granule-swizzled
    __shared__ __align__(16) __half Plh[NSLOT * 784];  // 24.5KB gh (fp16)
    __shared__ __align__(16) uint4  Wl[12 * 512];      // 98KB W_hh K-chunks 6..7
    __shared__ float Bl[G_];
    __shared__ int s_end[NSLOT], s_row[NSLOT], s_act[NSLOT], s_nxt[NSLOT];
    __shared__ int cur;

    const int tid = threadIdx.x;
    const int lane = tid & 63, w = tid >> 6;
    const int s = tid >> 5, g32 = tid & 31, e0 = g32 * 8;
    const int col = lane & 15, lq = lane >> 4;

    f16x8 wr[36];
    {
        const f16x8* wp = (const f16x8*)(WhhR + (size_t)tid * 36);
        #pragma unroll
        for (int i = 0; i < 36; ++i) wr[i] = wp[i];
    }
    #pragma unroll
    for (int i = 0; i < 12; ++i) Wl[i * 512 + tid] = WhhL[i * 512 + tid];
    if (tid < 384) { Bl[tid] = bhh[tid]; Bl[tid + 384] = bhh[tid + 384]; }
    { const uint4 z4 = {0u, 0u, 0u, 0u}; *(uint4*)((char*)Hl + tid * 16) = z4; }

    const int NQ = qctl[0];
    const int gb = blockIdx.x;
    const int lo = (int)(((long long)NQ * gb) >> 8);
    const int hi = (int)(((long long)NQ * (gb + 1)) >> 8);
    if (tid == 0) cur = lo + NSLOT;
    __syncthreads();

    {
        int e = -1;
        if (lo + s < hi) e = queue[lo + s];
        if (e >= 0) {
            const int ln = e & 1023, st = (e >> 10) & 511, nb = e >> 19;
            uint4 hseed;
            if (st == 0) {
                const float4 a = *(const float4*)(h0 + nb * 256 + e0);
                const float4 b = *(const float4*)(h0 + nb * 256 + e0 + 4);
                hseed = cvt8(a, b);
                if (g32 == 0) { s_row[s] = nb * T_; s_end[s] = nb * T_ + ln; }
            } else {
                hseed = *(const uint4*)(hs2 + (size_t)(nb * T_ + st) * 128 + g32 * 4);
                if (g32 == 0) { s_row[s] = nb * T_ + st + 1; s_end[s] = nb * T_ + st + ln; }
            }
            *(uint4*)((char*)Hl + s * 512 + ((g32 ^ (s & 7)) << 4)) = hseed;
            if (g32 == 0) {
                s_act[s] = 1;
                const int p = atomicAdd(&cur, 1);
                s_nxt[s] = (p < hi) ? queue[p] : -1;
            }
        } else if (g32 == 0) {
            s_act[s] = 0; s_nxt[s] = -1; s_row[s] = 0; s_end[s] = 0;
        }
    }
    __syncthreads();

    for (;;) {
        bool alive = false;
        #pragma unroll
        for (int i = 0; i < NSLOT; ++i) alive |= (s_act[i] != 0);
        if (!alive) break;

        // ---- phase X ----
        const int myrow = s_row[s];
        const int nxte = s_nxt[s];
        const __half* grow = gx + (size_t)myrow * G_;
        const f16x8 gr = *(const f16x8*)(grow + e0);
        const f16x8 gz = *(const f16x8*)(grow + 256 + e0);
        const f16x8 gn = *(const f16x8*)(grow + 512 + e0);
        uint4 su = {0u, 0u, 0u, 0u};
        if (nxte >= 0) {
            const int st = (nxte >> 10) & 511, nb = nxte >> 19;
            if (st == 0) {
                const float4 a = *(const float4*)(h0 + nb * 256 + e0);
                const float4 b = *(const float4*)(h0 + nb * 256 + e0 + 4);
                su = cvt8(a, b);
            } else {
                su = *(const uint4*)(hs2 + (size_t)(nb * T_ + st) * 128 + g32 * 4);
            }
        }
        f16x8 bfv[8];
        #pragma unroll
        for (int c = 0; c < 8; ++c)
            bfv[c] = *(const f16x8*)((const char*)Hl + col * 512 +
                                     ((((c << 2) + lq) ^ (col & 7)) << 4));
        f32x4 acc[6];
        #pragma unroll
        for (int i = 0; i < 6; ++i) { const f32x4 z = {0.f, 0.f, 0.f, 0.f}; acc[i] = z; }
        #pragma unroll
        for (int c = 0; c < 6; ++c)
            #pragma unroll
            for (int i = 0; i < 6; ++i)
                acc[i] = __builtin_amdgcn_mfma_f32_16x16x32_f16(wr[i * 6 + c], bfv[c], acc[i], 0, 0, 0);
        #pragma unroll
        for (int c2 = 0; c2 < 2; ++c2)
            #pragma unroll
            for (int i = 0; i < 6; ++i) {
                const f16x8 wlt = *(const f16x8*)&Wl[(i * 2 + c2) * 512 + tid];
                acc[i] = __builtin_amdgcn_mfma_f32_16x16x32_f16(wlt, bfv[6 + c2], acc[i], 0, 0, 0);
            }
        #pragma unroll
        for (int i = 0; i < 6; ++i) {
            uint2 ph;
            ph.x = h2u(__floats2half2_rn(acc[i][0], acc[i][1]));
            ph.y = h2u(__floats2half2_rn(acc[i][2], acc[i][3]));
            *(uint2*)(Plh + col * 784 + (w * 96 + i * 16 + lq * 4)) = ph;
        }
        asm volatile("s_waitcnt lgkmcnt(0)" ::: "memory");
        __builtin_amdgcn_s_barrier();

        // ---- phase Y ----
        if (s_act[s]) {
            const __half* Pr = Plh + s * 784;
            const f16x8 R  = *(const f16x8*)(Pr + e0);
            const f16x8 Z  = *(const f16x8*)(Pr + 256 + e0);
            const f16x8 Nn = *(const f16x8*)(Pr + 512 + e0);
            const f32x4 br0 = *(const f32x4*)(Bl + e0),       br1 = *(const f32x4*)(Bl + e0 + 4);
            const f32x4 bz0 = *(const f32x4*)(Bl + 256 + e0), bz1 = *(const f32x4*)(Bl + 256 + e0 + 4);
            const f32x4 bn0 = *(const f32x4*)(Bl + 512 + e0), bn1 = *(const f32x4*)(Bl + 512 + e0 + 4);
            const uint4 hp4 = *(const uint4*)((const char*)Hl + s * 512 + ((g32 ^ (s & 7)) << 4));
            const __half2 q0 = u2h(hp4.x), q1 = u2h(hp4.y), q2 = u2h(hp4.z), q3 = u2h(hp4.w);
            const float hpv[8] = { __low2float(q0), __high2float(q0), __low2float(q1), __high2float(q1),
                                   __low2float(q2), __high2float(q2), __low2float(q3), __high2float(q3) };
            float hn[8];
            #pragma unroll
            for (int j = 0; j < 8; ++j) {
                const float ghr = (float)R[j]  + (j < 4 ? br0[j] : br1[j - 4]);
                const float ghz = (float)Z[j]  + (j < 4 ? bz0[j] : bz1[j - 4]);
                const float ghn = (float)Nn[j] + (j < 4 ? bn0[j] : bn1[j - 4]);
                const float rg = 1.f / (1.f + exp2f(-((float)gr[j] + ghr) * 1.44269504f));
                const float zg = 1.f / (1.f + exp2f(-((float)gz[j] + ghz) * 1.44269504f));
                const float nin = (float)gn[j] + rg * ghn;
                const float ex = exp2f(nin * 2.885390082f);
                const float ng = 1.f - 2.f / (ex + 1.f);
                hn[j] = (1.f - zg) * ng + zg * hpv[j];
            }
            uint4 hp;
            hp.x = h2u(__floats2half2_rn(hn[0], hn[1]));
            hp.y = h2u(__floats2half2_rn(hn[2], hn[3]));
            hp.z = h2u(__floats2half2_rn(hn[4], hn[5]));
            hp.w = h2u(__floats2half2_rn(hn[6], hn[7]));
            *(uint4*)(hs2 + (size_t)myrow * 128 + g32 * 4) = hp;
            if (myrow + 1 < s_end[s]) {
                *(uint4*)((char*)Hl + s * 512 + ((g32 ^ (s & 7)) << 4)) = hp;
                if (g32 == 0) s_row[s] = myrow + 1;
            } else if (nxte >= 0) {
                const int ln = nxte & 1023, st = (nxte >> 10) & 511, nb = nxte >> 19;
                *(uint4*)((char*)Hl + s * 512 + ((g32 ^ (s & 7)) << 4)) = su;
                if (g32 == 0) {
                    if (st == 0) { s_row[s] = nb * T_;          s_end[s] = nb * T_ + ln; }
                    else         { s_row[s] = nb * T_ + st + 1; s_end[s] = nb * T_ + st + ln; }
                    const int p = atomicAdd(&cur, 1);
                    s_nxt[s] = (p < hi) ? queue[p] : -1;
                }
            } else if (g32 == 0) {
                s_act[s] = 0;
            }
        }
        asm volatile("s_waitcnt lgkmcnt(0)" ::: "memory");
        __builtin_amdgcn_s_barrier();
    }
}

// ---------------------------------------------------------------------------
// Heads (unchanged, passed): one wave per output row, hs fp16.
// ---------------------------------------------------------------------------
__global__ __launch_bounds__(256)
void heads_kernel(const uint32_t* __restrict__ hs2, const float* __restrict__ Wa,
                  const float* __restrict__ ba, const float* __restrict__ Wc,
                  const float* __restrict__ bc, const int* __restrict__ action,
                  float* __restrict__ out)
{
    const int wid = threadIdx.x >> 6, lane = threadIdx.x & 63;
    const int row = blockIdx.x * 4 + wid;
    const uint2 hv2 = ((const uint2*)(hs2 + (size_t)row * 128))[lane];
    const __half2 ha = u2h(hv2.x), hb = u2h(hv2.y);
    const float h0f = __low2float(ha), h1f = __high2float(ha);
    const float h2f = __low2float(hb), h3f = __high2float(hb);
    float sums[11];
    #pragma unroll
    for (int n = 0; n < 11; ++n) {
        const float* wrow = (n < 10) ? (Wa + n * 256) : Wc;
        const float4 wv = ((const float4*)wrow)[lane];
        sums[n] = h0f * wv.x + h1f * wv.y + h2f * wv.z + h3f * wv.w;
    }
    #pragma unroll
    for (int n = 0; n < 11; ++n) {
        float v = sums[n];
        #pragma unroll
        for (int off = 32; off; off >>= 1) v += __shfl_xor(v, off);
        sums[n] = v;
    }
    float logits[10];
    #pragma unroll
    for (int n = 0; n < 10; ++n) logits[n] = sums[n] + ba[n];
    const float value = sums[10] + bc[0];
    float mx = logits[0];
    #pragma unroll
    for (int n = 1; n < 10; ++n) mx = fmaxf(mx, logits[n]);
    float ssum = 0.f, sdot = 0.f;
    #pragma unroll
    for (int n = 0; n < 10; ++n) {
        float d = logits[n] - mx;
        float e = exp2f(d * 1.44269504f);
        ssum += e; sdot += e * d;
    }
    const float lns = logf(ssum);
    const float lse = mx + lns;
    const float entropy = lns - sdot / ssum;
    const int a = action[row];
    float la = 0.f;
    #pragma unroll
    for (int n = 0; n < 10; ++n) la = (n == a) ? logits[n] : la;
    if (lane == 0) {
        out[row] = value;
        out[BT_ + row] = la - lse;
        out[2 * BT_ + row] = entropy;
    }
}

// ---------------------------------------------------------------------------
extern "C" void kernel_launch(void* const* d_in, const int* in_sizes, int n_in,
                              void* d_out, int out_size, void* d_ws, size_t ws_size,
                              hipStream_t stream)
{
    const float* obs    = (const float*)d_in[0];
    const int*   action = (const int*)d_in[1];
    const int*   masks  = (const int*)d_in[2];
    const float* h0     = (const float*)d_in[3];
    const float* W1     = (const float*)d_in[4];
    const float* b1     = (const float*)d_in[5];
    const float* Wih    = (const float*)d_in[6];
    const float* Whh    = (const float*)d_in[7];
    const float* bih    = (const float*)d_in[8];
    const float* bhh    = (const float*)d_in[9];
    const float* Wa     = (const float*)d_in[10];
    const float* ba     = (const float*)d_in[11];
    const float* Wc     = (const float*)d_in[12];
    const float* bc     = (const float*)d_in[13];
    float* out = (float*)d_out;

    char* p = (char*)d_ws;
    __half*   gx   = (__half*)p;    p += (size_t)BT_ * G_ * 2;      // 50.3 MB
    uint32_t* hs2  = (uint32_t*)p;  p += (size_t)BT_ * H_ * 2;      // 16.8 MB
    uint32_t* W1f  = (uint32_t*)p;  p += FEAT_ * OBS_ * 2;          // 131 KB (B-frag)
    uint32_t* Wihf = (uint32_t*)p;  p += G_ * FEAT_ * 2;            // 786 KB (B-frag)
    uint4*    WhhR = (uint4*)p;     p += 512 * 36 * 16;             // 295 KB
    uint4*    WhhL = (uint4*)p;     p += 12 * 512 * 16;             // 98 KB
    int*      queue= (int*)p;       p += B_ * 512 * 4;              // 131 KB
    int*      qctl = (int*)p;       p += 256;                       // [0]=tail

    // packs (pack_whh zeroes qctl) + segment queue build
    pack_bfrag<OBS_><<<128, 256, 0, stream>>>(W1, W1f, FEAT_ * OBS_ / 2);
    pack_bfrag<FEAT_><<<768, 256, 0, stream>>>(Wih, Wihf, G_ * FEAT_ / 2);
    pack_whh<<<384, 256, 0, stream>>>(Whh, (uint32_t*)WhhR, (uint32_t*)WhhL, qctl);
    seg_build<<<B_, 512, 0, stream>>>(masks, queue, &qctl[0]);
    // gx = relu(obs@W1^T+b1) @ Wih^T + bih  -- fused, B-operands in registers
    fused_gemm<<<1536, 512, 0, stream>>>(obs, (const uint4*)W1f, (const uint4*)Wihf, b1, bih, (uint32_t*)gx);
    // pre-pass: all h_prev==0 steps (elementwise, grid-stride)
    h0pre<<<2048, 256, 0, stream>>>(gx, bhh, masks, hs2);
    // MFMA slot-parallel recurrence (static slices, 2 barriers/iter, pre-pop)
    gru_mfma<<<256, 512, 0, stream>>>(gx, WhhR, WhhL, bhh, h0, queue, qctl, hs2);
    // heads
    heads_kernel<<<8192, 256, 0, stream>>>(hs2, Wa, ba, Wc, bc, action, out);
}